// Round 12
// baseline (116.367 us; speedup 1.0000x reference)
//
#include <hip/hip_runtime.h>
#include <math.h>

#define NB 4
#define CC 128
#define HW 784            // 28*28
#define KK 64
#define DD 512
#define TD 8              // d-rows per block
#define BLK 832           // 13 waves
#define CCH 16            // channels per staged chunk
#define NCH (CC / CCH)    // 8 chunks
#define CHUNK_FLOATS (CCH * HW)       // 12544 floats = 49 KB
#define CHUNK_F4 (CHUNK_FLOATS / 4)   // 3136 float4

// Double-buffered LDS staging of x (T14 issue-early/write-late):
//   per 16-channel chunk, all 832 threads cooperatively load the CONTIGUOUS
//   49 KB chunk x[n, c0:c0+16, :] as coalesced float4 into registers EARLY,
//   compute the previous chunk from LDS, then ds_write and barrier.
//   HBM-cold latency (caches are flushed by the harness's 3.7 GB of poison
//   fills between replays — proven by R2's rinv profile) hides under a full
//   chunk of compute instead of stalling every load batch.
//   - thread t owns pixel p=t (t<784): 8 conv dots + sumsq from LDS x
//   - weights staged transposed in LDS, 2 broadcast ds_read_b128 per c
//   - feat overlays xbuf[0] after the main loop (LDS total ~102 KB)
//   - waves 0..7: per-row softmax-weighted mean over P=784
//   - vlad[n,k,d] is k-independent (softmax over the spatial axis is invariant
//     to the per-(k,d) centroid shift) -> broadcast write via LDS
__global__ __launch_bounds__(BLK) void netvlad_fused_kernel(
    const float* __restrict__ x, const float* __restrict__ w,
    const float* __restrict__ b, float* __restrict__ out)
{
    __shared__ float xbuf[2][CHUNK_FLOATS];   // 98 KB
    __shared__ float w_s[CC][TD];             // 4 KB, transposed [c][j]
    __shared__ float g_s[TD];

    const int tid = threadIdx.x;
    const int n  = blockIdx.x >> 6;
    const int d0 = (blockIdx.x & 63) * TD;
    const bool act = tid < HW;
    const int p = act ? tid : 0;

    // stage the 8x128 weight tile transposed (one-time, 4 KB)
    for (int i = tid; i < CC * TD; i += BLK) {
        int c = i >> 3, j = i & 7;
        w_s[c][j] = w[(size_t)(d0 + j) * CC + c];
    }

    const float4* xsrc = (const float4*)(x + (size_t)n * CC * HW);

    // prologue: stage chunk 0 into xbuf[0]
    float4 st[4];
    #pragma unroll
    for (int u = 0; u < 4; ++u) {
        int i = tid + u * BLK;
        if (i < CHUNK_F4) st[u] = xsrc[i];
    }
    #pragma unroll
    for (int u = 0; u < 4; ++u) {
        int i = tid + u * BLK;
        if (i < CHUNK_F4) *(float4*)&xbuf[0][i * 4] = st[u];
    }
    __syncthreads();

    float acc[TD];
    #pragma unroll
    for (int j = 0; j < TD; ++j) acc[j] = 0.f;
    float sq = 0.f;

    for (int k = 0; k < NCH; ++k) {
        // ISSUE chunk k+1 loads early (HBM latency hides under compute below)
        if (k + 1 < NCH) {
            #pragma unroll
            for (int u = 0; u < 4; ++u) {
                int i = tid + u * BLK;
                if (i < CHUNK_F4) st[u] = xsrc[(size_t)(k + 1) * CHUNK_F4 + i];
            }
        }
        // COMPUTE chunk k from LDS (conflict-free: lane i reads word p0+i)
        const float* xb = &xbuf[k & 1][0];
        #pragma unroll
        for (int c = 0; c < CCH; ++c) {
            float xv = xb[c * HW + p];
            float4 wlo = *(const float4*)&w_s[k * CCH + c][0];   // broadcast
            float4 whi = *(const float4*)&w_s[k * CCH + c][4];   // broadcast
            sq = fmaf(xv, xv, sq);
            acc[0] = fmaf(wlo.x, xv, acc[0]);
            acc[1] = fmaf(wlo.y, xv, acc[1]);
            acc[2] = fmaf(wlo.z, xv, acc[2]);
            acc[3] = fmaf(wlo.w, xv, acc[3]);
            acc[4] = fmaf(whi.x, xv, acc[4]);
            acc[5] = fmaf(whi.y, xv, acc[5]);
            acc[6] = fmaf(whi.z, xv, acc[6]);
            acc[7] = fmaf(whi.w, xv, acc[7]);
        }
        // WRITE chunk k+1 to the other buffer, then barrier
        if (k + 1 < NCH) {
            #pragma unroll
            for (int u = 0; u < 4; ++u) {
                int i = tid + u * BLK;
                if (i < CHUNK_F4) *(float4*)&xbuf[(k + 1) & 1][i * 4] = st[u];
            }
        }
        __syncthreads();
    }

    // feat overlays xbuf[0] (all chunk reads are complete past the last barrier)
    float* feat_lds = &xbuf[0][0];    // [TD][HW] row-major, 25 KB
    if (act) {
        float r = 1.0f / fmaxf(sqrtf(sq), 1e-12f);
        #pragma unroll
        for (int j = 0; j < TD; ++j)
            feat_lds[j * HW + tid] = fmaf(acc[j], r, b[d0 + j]);
    }
    __syncthreads();

    // Per-row softmax-weighted mean over P=784; wave j (j<8) handles row j.
    const int lane = tid & 63;
    const int wave = tid >> 6;
    if (wave < TD) {
        const int j = wave;
        float m = -INFINITY;
        for (int q = lane; q < HW; q += 64) m = fmaxf(m, feat_lds[j * HW + q]);
        #pragma unroll
        for (int off = 32; off; off >>= 1) m = fmaxf(m, __shfl_xor(m, off, 64));
        float s = 0.f, ws = 0.f;
        for (int q = lane; q < HW; q += 64) {
            float f = feat_lds[j * HW + q];
            float e = __expf(f - m);
            s += e;
            ws = fmaf(e, f, ws);
        }
        #pragma unroll
        for (int off = 32; off; off >>= 1) {
            s  += __shfl_xor(s, off, 64);
            ws += __shfl_xor(ws, off, 64);
        }
        if (lane == 0) g_s[j] = ws / s;
    }
    __syncthreads();

    // Broadcast across k with a coalesced write: block owns out[n, :, d0:d0+8]
    if (tid < KK * TD) {
        int k = tid >> 3, j = tid & 7;
        out[(size_t)n * KK * DD + (size_t)k * DD + d0 + j] = g_s[j];
    }
}

extern "C" void kernel_launch(void* const* d_in, const int* in_sizes, int n_in,
                              void* d_out, int out_size, void* d_ws, size_t ws_size,
                              hipStream_t stream) {
    const float* x = (const float*)d_in[0];   // (4,128,28,28)
    const float* w = (const float*)d_in[1];   // (512,128)
    const float* b = (const float*)d_in[2];   // (512,)
    // d_in[3] = centroids (64,512): provably unused — softmax over the spatial
    // axis is invariant to the per-(k,d) constant shift, so vlad[n,k,d] is
    // identical for all k.
    float* out = (float*)d_out;               // (4,64,512) fp32

    netvlad_fused_kernel<<<NB * (DD / TD), BLK, 0, stream>>>(x, w, b, out);
}

// Round 13
// 19.188 us; speedup vs baseline: 6.0647x; 6.0647x over previous
//
#include <hip/hip_runtime.h>
#include <math.h>

#define NB 4
#define CC 128
#define HW 784        // 28*28
#define KK 64
#define DD 512
#define TD 16         // d-rows per block (key change: halves x L2 traffic)
#define PXB 392       // pixels per block (half of 784)
#define CH 64         // channels per c-half
#define HTH 416       // threads per c-half (392 active + wave pad)
#define BLK 832       // 13 waves

// K1: block = (n, 16-d-group, pixel-half); thread = (pixel, c-half).
// L2 x-traffic = (DD/TD) * 6.4 MB = 205 MB (was 411 MB at TD=8) -> ~6 us at
// the 34.5 TB/s L2 ceiling, which R10+R12 identified as the kernel's binding
// constraint. All 256 CUs stay busy via the pixel-half split (R8-proven
// partial-softmax structure: |feat| <= ~0.8 so exp needs no max pass).
// XCD-aware bid decode: blocks land so XCD i serves n = i/2 only ->
// per-XCD L2 working set = one x[n] = 1.6 MB < 4 MB (survives cold caches).
__global__ __launch_bounds__(BLK) void netvlad_gemm_partial(
    const float* __restrict__ x, const float* __restrict__ w,
    const float* __restrict__ b, float2* __restrict__ pws)
{
    __shared__ float w_s[CC][TD];       // 8 KB transposed [c][j]
    __shared__ float acc_s[TD][PXB];    // 24.5 KB
    __shared__ float sq_s[PXB];         // 1.5 KB

    const int tid  = threadIdx.x;
    // XCD-aware decode (default dispatch: xcd = bid % 8). Bijective:
    // xcd in 0..7 -> n = xcd>>1; slot 0..31 -> dg = 2*(slot>>1) + (xcd&1),
    // h = slot&1. Each XCD touches exactly one n.
    const int bid  = blockIdx.x;
    const int xcd  = bid & 7;
    const int slot = bid >> 3;
    const int n    = xcd >> 1;
    const int dg   = ((slot >> 1) << 1) | (xcd & 1);
    const int h    = slot & 1;
    const int d0   = dg * TD;
    const int p0   = h * PXB;

    // stage the 16x128 weight tile transposed (one-time)
    for (int i = tid; i < CC * TD; i += BLK) {
        int c = i >> 4, j = i & 15;
        w_s[c][j] = w[(size_t)(d0 + j) * CC + c];
    }

    const int  ch    = (tid >= HTH) ? 1 : 0;
    const int  qr    = tid - ch * HTH;
    const bool act   = qr < PXB;
    const int  p_loc = act ? qr : 0;     // clamp keeps loads in-bounds
    const int  cb    = ch * CH;

    __syncthreads();

    const float* xp = x + (size_t)n * CC * HW + (size_t)cb * HW + (p0 + p_loc);

    float acc[TD];
    #pragma unroll
    for (int j = 0; j < TD; ++j) acc[j] = 0.f;
    float sq = 0.f;

    // 8-deep load batches (proven adequate pipelining)
    for (int cc = 0; cc < CH; cc += 8) {
        float xv[8];
        #pragma unroll
        for (int u = 0; u < 8; ++u)
            xv[u] = xp[(size_t)(cc + u) * HW];
        #pragma unroll
        for (int u = 0; u < 8; ++u) {
            const int c = cb + cc + u;
            float4 w0 = *(const float4*)&w_s[c][0];    // uniform -> broadcast
            float4 w1 = *(const float4*)&w_s[c][4];
            float4 w2 = *(const float4*)&w_s[c][8];
            float4 w3 = *(const float4*)&w_s[c][12];
            float xvu = xv[u];
            sq = fmaf(xvu, xvu, sq);
            acc[0]  = fmaf(w0.x, xvu, acc[0]);
            acc[1]  = fmaf(w0.y, xvu, acc[1]);
            acc[2]  = fmaf(w0.z, xvu, acc[2]);
            acc[3]  = fmaf(w0.w, xvu, acc[3]);
            acc[4]  = fmaf(w1.x, xvu, acc[4]);
            acc[5]  = fmaf(w1.y, xvu, acc[5]);
            acc[6]  = fmaf(w1.z, xvu, acc[6]);
            acc[7]  = fmaf(w1.w, xvu, acc[7]);
            acc[8]  = fmaf(w2.x, xvu, acc[8]);
            acc[9]  = fmaf(w2.y, xvu, acc[9]);
            acc[10] = fmaf(w2.z, xvu, acc[10]);
            acc[11] = fmaf(w2.w, xvu, acc[11]);
            acc[12] = fmaf(w3.x, xvu, acc[12]);
            acc[13] = fmaf(w3.y, xvu, acc[13]);
            acc[14] = fmaf(w3.z, xvu, acc[14]);
            acc[15] = fmaf(w3.w, xvu, acc[15]);
        }
    }

    // combine the two c-halves through LDS
    if (act && ch == 0) {
        sq_s[p_loc] = sq;
        #pragma unroll
        for (int j = 0; j < TD; ++j) acc_s[j][p_loc] = acc[j];
    }
    __syncthreads();
    if (act && ch == 1) {
        float r = 1.0f / fmaxf(sqrtf(sq_s[p_loc] + sq), 1e-12f);
        #pragma unroll
        for (int j = 0; j < TD; ++j)
            acc_s[j][p_loc] = fmaf(acc_s[j][p_loc] + acc[j], r, b[d0 + j]);
    }
    __syncthreads();

    // partial softmax sums over this block's 392 pixels; 8 waves x 2 rows.
    // No max subtraction: |feat| bounded ~0.8 (normalized x, small w rows) —
    // shift-invariance makes partials exact (R8-verified).
    const int lane = tid & 63;
    const int wave = tid >> 6;
    if (wave < 8) {
        #pragma unroll
        for (int rr = 0; rr < 2; ++rr) {
            const int j = wave * 2 + rr;
            float s = 0.f, ws = 0.f;
            for (int q = lane; q < PXB; q += 64) {
                float f = acc_s[j][q];
                float e = __expf(f);
                s += e;
                ws = fmaf(e, f, ws);
            }
            #pragma unroll
            for (int off = 32; off; off >>= 1) {
                s  += __shfl_xor(s, off, 64);
                ws += __shfl_xor(ws, off, 64);
            }
            if (lane == 0)
                pws[(size_t)(n * DD + d0 + j) * 2 + h] = make_float2(s, ws);
        }
    }
}

// K2: merge the two pixel-half partials per (n,d) row, divide, broadcast over k.
__global__ __launch_bounds__(512) void netvlad_finalize(
    const float2* __restrict__ pws, float* __restrict__ out)
{
    const int d  = threadIdx.x;
    const int n  = blockIdx.x >> 3;
    const int ks = (blockIdx.x & 7) * 8;
    float2 a = pws[(size_t)(n * DD + d) * 2 + 0];
    float2 c = pws[(size_t)(n * DD + d) * 2 + 1];
    float g = (a.y + c.y) / (a.x + c.x);
    #pragma unroll
    for (int i = 0; i < 8; ++i)
        out[(size_t)n * KK * DD + (size_t)(ks + i) * DD + d] = g;  // coalesced
}

extern "C" void kernel_launch(void* const* d_in, const int* in_sizes, int n_in,
                              void* d_out, int out_size, void* d_ws, size_t ws_size,
                              hipStream_t stream) {
    const float* x = (const float*)d_in[0];   // (4,128,28,28)
    const float* w = (const float*)d_in[1];   // (512,128)
    const float* b = (const float*)d_in[2];   // (512,)
    // d_in[3] = centroids (64,512): provably unused — softmax over the spatial
    // axis is invariant to the per-(k,d) constant shift, so vlad[n,k,d] is
    // identical for all k.
    float2* pws = (float2*)d_ws;              // 4096 float2 = 32 KB partials
    float* out  = (float*)d_out;              // (4,64,512) fp32

    netvlad_gemm_partial<<<NB * (DD / TD) * 2, BLK, 0, stream>>>(x, w, b, pws);
    netvlad_finalize<<<32, 512, 0, stream>>>(pws, out);
}